// Round 1
// baseline (994.256 us; speedup 1.0000x reference)
//
#include <hip/hip_runtime.h>

typedef __bf16 bf16;
typedef __bf16 bf16x8 __attribute__((ext_vector_type(8)));
typedef __bf16 bf16x4 __attribute__((ext_vector_type(4)));
typedef float floatx4 __attribute__((ext_vector_type(4)));

#define NB 4
#define NT 2048
#define NC 2048
#define NH 16
#define ND 128
#define N3 6144

__device__ __forceinline__ void load_lds16(const void* gptr, void* ldsptr) {
  __builtin_amdgcn_global_load_lds(
      (const __attribute__((address_space(1))) unsigned int*)gptr,
      (__attribute__((address_space(3))) unsigned int*)ldsptr, 16, 0, 0);
}

// ---------------- cast fp32 -> bf16 (4 elts/thread) ----------------
__global__ __launch_bounds__(256) void cast_f32_bf16(const float* __restrict__ in,
                                                     bf16* __restrict__ out) {
  const int i = blockIdx.x * 256 + threadIdx.x;
  const float4 v = ((const float4*)in)[i];
  bf16x4 o;
  o[0] = (bf16)v.x; o[1] = (bf16)v.y; o[2] = (bf16)v.z; o[3] = (bf16)v.w;
  ((bf16x4*)out)[i] = o;
}

// ------------- transpose+cast: in[R][Cc] f32 -> out[Cc][R] bf16 -------------
__global__ __launch_bounds__(256) void transpose_cast(const float* __restrict__ in,
                                                      bf16* __restrict__ out,
                                                      int R, int Cc) {
  __shared__ float tile[64][65];
  const int r0 = blockIdx.y * 64, c0 = blockIdx.x * 64;
  const int rr = threadIdx.x >> 6, cc = threadIdx.x & 63;
#pragma unroll
  for (int i = 0; i < 16; ++i)
    tile[rr + i * 4][cc] = in[(size_t)(r0 + rr + i * 4) * Cc + c0 + cc];
  __syncthreads();
#pragma unroll
  for (int i = 0; i < 16; ++i)
    out[(size_t)(c0 + rr + i * 4) * R + r0 + cc] = (bf16)tile[cc][rr + i * 4];
}

// ------------- GEMM: C[M][N] = A[M][K] * Bt[N][K]^T (m97 structure) -------------
template <typename OutT>
__global__ __launch_bounds__(256) void gemm_bt(const bf16* __restrict__ A,
                                               const bf16* __restrict__ Bt,
                                               OutT* __restrict__ C,
                                               int M, int N, int K) {
  __shared__ bf16 As[128 * 32];
  __shared__ bf16 Bs[128 * 32];
  const int tid = threadIdx.x;
  const int w = tid >> 6, l = tid & 63, quad = l >> 4, l16 = l & 15;
  const int wm = (w >> 1) * 64, wn = (w & 1) * 64;
  const int m0 = blockIdx.y * 128, n0 = blockIdx.x * 128;

  const floatx4 fzero = {0.f, 0.f, 0.f, 0.f};
  floatx4 acc[4][4];
#pragma unroll
  for (int i = 0; i < 4; ++i)
#pragma unroll
    for (int j = 0; j < 4; ++j) acc[i][j] = fzero;

  for (int k0 = 0; k0 < K; k0 += 32) {
#pragma unroll
    for (int i = 0; i < 2; ++i) {
      const int f = (w * 2 + i) * 64 + l;
      const int r = f >> 2, c = f & 3;  // 4 chunks of 8 bf16 per 32-wide row
      load_lds16(A + (size_t)(m0 + r) * K + k0 + c * 8, As + (w * 2 + i) * 512);
      load_lds16(Bt + (size_t)(n0 + r) * K + k0 + c * 8, Bs + (w * 2 + i) * 512);
    }
    __syncthreads();
    bf16x8 af[4], bfrag[4];
#pragma unroll
    for (int mi = 0; mi < 4; ++mi)
      af[mi] = *(const bf16x8*)(As + (wm + mi * 16 + l16) * 32 + quad * 8);
#pragma unroll
    for (int ni = 0; ni < 4; ++ni)
      bfrag[ni] = *(const bf16x8*)(Bs + (wn + ni * 16 + l16) * 32 + quad * 8);
#pragma unroll
    for (int mi = 0; mi < 4; ++mi)
#pragma unroll
      for (int ni = 0; ni < 4; ++ni)
        acc[mi][ni] = __builtin_amdgcn_mfma_f32_16x16x32_bf16(af[mi], bfrag[ni],
                                                              acc[mi][ni], 0, 0, 0);
    __syncthreads();
  }
  // C/D layout: col = lane&15, row = quad*4 + reg
#pragma unroll
  for (int mi = 0; mi < 4; ++mi)
#pragma unroll
    for (int ni = 0; ni < 4; ++ni) {
      const int row = m0 + wm + mi * 16 + quad * 4;
      const int col = n0 + wn + ni * 16 + l16;
#pragma unroll
      for (int r = 0; r < 4; ++r)
        C[(size_t)(row + r) * N + col] = (OutT)acc[mi][ni][r];
    }
}

// ------------- RoPE in place on Q and K sections of qkv -------------
__global__ __launch_bounds__(256) void rope_kernel(bf16* __restrict__ qkv) {
  const int row = blockIdx.x;       // b*T + t
  const int t = row & (NT - 1);
  const float tt = (float)t;
#pragma unroll
  for (int i = 0; i < 4; ++i) {
    const int idx = threadIdx.x + i * 256;  // 0..1023 -> (h, d<64)
    const int h = idx >> 6, d = idx & 63;
    const float invf = exp2f((float)d * (-13.287712379549449f / 64.f));  // 10000^(-d/64)
    const float ang = tt * invf;
    float s, c;
    sincosf(ang, &s, &c);
    const size_t base = (size_t)row * N3 + h * ND + d;
    {  // Q
      const float x1 = (float)qkv[base], x2 = (float)qkv[base + 64];
      qkv[base]      = (bf16)(x1 * c - x2 * s);
      qkv[base + 64] = (bf16)(x2 * c + x1 * s);
    }
    {  // K
      const float x1 = (float)qkv[base + NC], x2 = (float)qkv[base + NC + 64];
      qkv[base + NC]      = (bf16)(x1 * c - x2 * s);
      qkv[base + NC + 64] = (bf16)(x2 * c + x1 * s);
    }
  }
}

// ------------- V transpose: qkv V-section -> vt[(b,h,d,t)] -------------
__global__ __launch_bounds__(256) void vtrans_kernel(const bf16* __restrict__ qkv,
                                                     bf16* __restrict__ vt) {
  __shared__ bf16 tile[64][136];
  const int t0 = blockIdx.x * 64, h = blockIdx.y, b = blockIdx.z;
  const int tid = threadIdx.x;
#pragma unroll
  for (int i = 0; i < 4; ++i) {
    const int f = tid + i * 256;  // 1024 chunks of 8
    const int r = f >> 4, c8 = f & 15;
    const bf16x8 v = *(const bf16x8*)(qkv + (size_t)(b * NT + t0 + r) * N3 + 2 * NC + h * ND + c8 * 8);
    *(bf16x8*)(&tile[r][c8 * 8]) = v;
  }
  __syncthreads();
#pragma unroll
  for (int i = 0; i < 8; ++i) {
    const int f = tid + i * 256;  // 2048 chunks of 4 along t
    const int d = f >> 4, c4 = f & 15;
    bf16x4 o;
#pragma unroll
    for (int j = 0; j < 4; ++j) o[j] = tile[c4 * 4 + j][d];
    *(bf16x4*)(vt + ((size_t)((b * NH + h) * ND + d)) * NT + t0 + c4 * 4) = o;
  }
}

// ------------- flash attention: 128-q tile/block, 64-kv tiles -------------
__global__ __launch_bounds__(256) void attn_kernel(const bf16* __restrict__ qkv,
                                                   const bf16* __restrict__ vt,
                                                   bf16* __restrict__ y) {
  __shared__ bf16 Ks[64 * 128];   // [kv][d], xor-swizzled 16B chunks
  __shared__ bf16 Vs[128 * 64];   // [d][kv], xor-swizzled 16B chunks
  __shared__ bf16 Ps[128 * 72];   // [q][kv] padded (+8)

  const int qt = blockIdx.x, h = blockIdx.y, b = blockIdx.z;
  const int q0 = qt * 128;
  const int tid = threadIdx.x;
  const int w = tid >> 6, l = tid & 63, quad = l >> 4, l16 = l & 15;

  // Q A-fragments straight from global (RoPE'd): Q[q=l16][d=quad*8+j]
  bf16x8 aq[2][4];
#pragma unroll
  for (int mi = 0; mi < 2; ++mi)
#pragma unroll
    for (int ks = 0; ks < 4; ++ks) {
      const size_t row = (size_t)(b * NT + q0 + w * 32 + mi * 16 + l16);
      aq[mi][ks] = *(const bf16x8*)(qkv + row * N3 + h * ND + ks * 32 + quad * 8);
    }

  const floatx4 fzero = {0.f, 0.f, 0.f, 0.f};
  floatx4 acc_o[2][8];
#pragma unroll
  for (int mi = 0; mi < 2; ++mi)
#pragma unroll
    for (int ni = 0; ni < 8; ++ni) acc_o[mi][ni] = fzero;
  float mrow[2][4], lrow[2][4];
#pragma unroll
  for (int mi = 0; mi < 2; ++mi)
#pragma unroll
    for (int r = 0; r < 4; ++r) { mrow[mi][r] = -1e30f; lrow[mi][r] = 0.f; }

  const float SCL = 0.08838834764831845f * 1.4426950408889634f;  // 1/sqrt(128)*log2(e)
  const int ntiles = q0 / 64 + 2;

  for (int it = 0; it < ntiles; ++it) {
    const int kv0 = it * 64;
#pragma unroll
    for (int i = 0; i < 4; ++i) {
      const int fb = i * 256 + w * 64;  // wave-uniform chunk base
      const int f = fb + l;
      {  // K tile: 64 kv rows x 16 chunks, slot cs holds global chunk cs^(row&15)
        const int r = f >> 4, cs = f & 15, c = cs ^ (r & 15);
        load_lds16(qkv + (size_t)(b * NT + kv0 + r) * N3 + NC + h * ND + c * 8, Ks + fb * 8);
      }
      {  // V^T tile: 128 d rows x 8 chunks, slot cs holds global chunk cs^(row&7)
        const int r = f >> 3, cs = f & 7, c = cs ^ (r & 7);
        load_lds16(vt + ((size_t)((b * NH + h) * ND + r)) * NT + kv0 + c * 8, Vs + fb * 8);
      }
    }
    __syncthreads();

    // S = Q K^T
    floatx4 accs[2][4];
#pragma unroll
    for (int mi = 0; mi < 2; ++mi)
#pragma unroll
      for (int ni = 0; ni < 4; ++ni) accs[mi][ni] = fzero;
#pragma unroll
    for (int ks = 0; ks < 4; ++ks) {
      bf16x8 bk[4];
#pragma unroll
      for (int ni = 0; ni < 4; ++ni) {
        const int r = ni * 16 + l16;
        const int slot = (ks * 4 + quad) ^ l16;
        bk[ni] = *(const bf16x8*)(Ks + r * 128 + slot * 8);
      }
#pragma unroll
      for (int mi = 0; mi < 2; ++mi)
#pragma unroll
        for (int ni = 0; ni < 4; ++ni)
          accs[mi][ni] = __builtin_amdgcn_mfma_f32_16x16x32_bf16(aq[mi][ks], bk[ni],
                                                                 accs[mi][ni], 0, 0, 0);
    }

    // mask + online softmax (log2 domain)
    const bool need_mask = (kv0 + 63 > q0 + w * 32);
#pragma unroll
    for (int mi = 0; mi < 2; ++mi) {
      float alpha[4];
#pragma unroll
      for (int r = 0; r < 4; ++r) {
        float mx = -1e30f;
#pragma unroll
        for (int ni = 0; ni < 4; ++ni) {
          float sv = accs[mi][ni][r] * SCL;
          if (need_mask) {
            const int qg = q0 + w * 32 + mi * 16 + quad * 4 + r;
            const int kg = kv0 + ni * 16 + l16;
            if (kg > qg) sv = -1e30f;
          }
          accs[mi][ni][r] = sv;
          mx = fmaxf(mx, sv);
        }
        mx = fmaxf(mx, __shfl_xor(mx, 1));
        mx = fmaxf(mx, __shfl_xor(mx, 2));
        mx = fmaxf(mx, __shfl_xor(mx, 4));
        mx = fmaxf(mx, __shfl_xor(mx, 8));
        const float mold = mrow[mi][r];
        const float mnew = fmaxf(mold, mx);
        const float al = exp2f(mold - mnew);
        float rs = 0.f;
#pragma unroll
        for (int ni = 0; ni < 4; ++ni) {
          const float p = exp2f(accs[mi][ni][r] - mnew);
          accs[mi][ni][r] = p;
          rs += p;
        }
        rs += __shfl_xor(rs, 1);
        rs += __shfl_xor(rs, 2);
        rs += __shfl_xor(rs, 4);
        rs += __shfl_xor(rs, 8);
        lrow[mi][r] = lrow[mi][r] * al + rs;
        mrow[mi][r] = mnew;
        alpha[r] = al;
      }
#pragma unroll
      for (int ni = 0; ni < 8; ++ni)
#pragma unroll
        for (int r = 0; r < 4; ++r) acc_o[mi][ni][r] *= alpha[r];
      // P -> LDS (wave-private rows; per-wave DS ordering guarantees write->read)
#pragma unroll
      for (int ni = 0; ni < 4; ++ni)
#pragma unroll
        for (int r = 0; r < 4; ++r)
          Ps[(w * 32 + mi * 16 + quad * 4 + r) * 72 + ni * 16 + l16] = (bf16)accs[mi][ni][r];
    }

    // O += P V
#pragma unroll
    for (int s = 0; s < 2; ++s) {
      bf16x8 ap[2];
#pragma unroll
      for (int mi = 0; mi < 2; ++mi)
        ap[mi] = *(const bf16x8*)(Ps + (w * 32 + mi * 16 + l16) * 72 + s * 32 + quad * 8);
#pragma unroll
      for (int ni = 0; ni < 8; ++ni) {
        const int r = ni * 16 + l16;
        const int slot = (s * 4 + quad) ^ (l16 & 7);
        const bf16x8 bv = *(const bf16x8*)(Vs + r * 64 + slot * 8);
#pragma unroll
        for (int mi = 0; mi < 2; ++mi)
          acc_o[mi][ni] = __builtin_amdgcn_mfma_f32_16x16x32_bf16(ap[mi], bv,
                                                                  acc_o[mi][ni], 0, 0, 0);
      }
    }
    __syncthreads();
  }

#pragma unroll
  for (int mi = 0; mi < 2; ++mi) {
    float inv[4];
#pragma unroll
    for (int r = 0; r < 4; ++r) inv[r] = 1.f / lrow[mi][r];
#pragma unroll
    for (int ni = 0; ni < 8; ++ni) {
      const int dd = ni * 16 + l16;
#pragma unroll
      for (int r = 0; r < 4; ++r) {
        const int qq = q0 + w * 32 + mi * 16 + quad * 4 + r;
        y[(size_t)(b * NT + qq) * NC + h * ND + dd] = (bf16)(acc_o[mi][ni][r] * inv[r]);
      }
    }
  }
}

extern "C" void kernel_launch(void* const* d_in, const int* in_sizes, int n_in,
                              void* d_out, int out_size, void* d_ws, size_t ws_size,
                              hipStream_t stream) {
  const float* x      = (const float*)d_in[0];  // (4,2048,2048)
  const float* w_attn = (const float*)d_in[1];  // (2048,6144)
  const float* w_proj = (const float*)d_in[2];  // (2048,2048)
  float* out = (float*)d_out;
  char* ws = (char*)d_ws;

  // workspace layout (aliased): total 176,160,768 B
  bf16* qkv = (bf16*)(ws);                 // [8192][6144]  100,663,296 B
  bf16* xb  = (bf16*)(ws + 100663296);     // [8192][2048]   33,554,432 B
  bf16* vt  = xb;                          // aliases xb (xb dead after GEMM1)
  bf16* wab = (bf16*)(ws + 134217728);     // [6144][2048]   25,165,824 B
  bf16* y   = wab;                         // aliases wab (wab dead after GEMM1)
  bf16* wpb = (bf16*)(ws + 167772160);     // [2048][2048]    8,388,608 B

  cast_f32_bf16<<<dim3(16384), dim3(256), 0, stream>>>(x, xb);
  transpose_cast<<<dim3(96, 32), dim3(256), 0, stream>>>(w_attn, wab, 2048, 6144);
  transpose_cast<<<dim3(32, 32), dim3(256), 0, stream>>>(w_proj, wpb, 2048, 2048);
  gemm_bt<bf16><<<dim3(48, 64), dim3(256), 0, stream>>>(xb, wab, qkv, 8192, 6144, 2048);
  rope_kernel<<<dim3(8192), dim3(256), 0, stream>>>(qkv);
  vtrans_kernel<<<dim3(32, 16, 4), dim3(256), 0, stream>>>(qkv, vt);
  attn_kernel<<<dim3(16, 16, 4), dim3(256), 0, stream>>>(qkv, vt, y);
  gemm_bt<float><<<dim3(16, 64), dim3(256), 0, stream>>>(y, wpb, out, 8192, 2048, 2048);
}

// Round 2
// 742.938 us; speedup vs baseline: 1.3383x; 1.3383x over previous
//
#include <hip/hip_runtime.h>

typedef __bf16 bf16;
typedef __bf16 bf16x8 __attribute__((ext_vector_type(8)));
typedef __bf16 bf16x4 __attribute__((ext_vector_type(4)));
typedef __bf16 bf16x2 __attribute__((ext_vector_type(2)));
typedef float floatx4 __attribute__((ext_vector_type(4)));
typedef float floatx16 __attribute__((ext_vector_type(16)));

#define NB 4
#define NT 2048
#define NC 2048
#define NH 16
#define ND 128
#define N3 6144

__device__ __forceinline__ void load_lds16(const void* gptr, void* ldsptr) {
  __builtin_amdgcn_global_load_lds(
      (const __attribute__((address_space(1))) unsigned int*)gptr,
      (__attribute__((address_space(3))) unsigned int*)ldsptr, 16, 0, 0);
}

__device__ __forceinline__ unsigned pack2(float a, float b) {
  bf16x2 v;
  v[0] = (bf16)a; v[1] = (bf16)b;
  return __builtin_bit_cast(unsigned, v);
}

// ---------------- cast fp32 -> bf16 (4 elts/thread) ----------------
__global__ __launch_bounds__(256) void cast_f32_bf16(const float* __restrict__ in,
                                                     bf16* __restrict__ out) {
  const int i = blockIdx.x * 256 + threadIdx.x;
  const float4 v = ((const float4*)in)[i];
  bf16x4 o;
  o[0] = (bf16)v.x; o[1] = (bf16)v.y; o[2] = (bf16)v.z; o[3] = (bf16)v.w;
  ((bf16x4*)out)[i] = o;
}

// ------------- transpose+cast: in[R][Cc] f32 -> out[Cc][R] bf16 -------------
__global__ __launch_bounds__(256) void transpose_cast(const float* __restrict__ in,
                                                      bf16* __restrict__ out,
                                                      int R, int Cc) {
  __shared__ float tile[64][65];
  const int r0 = blockIdx.y * 64, c0 = blockIdx.x * 64;
  const int rr = threadIdx.x >> 6, cc = threadIdx.x & 63;
#pragma unroll
  for (int i = 0; i < 16; ++i)
    tile[rr + i * 4][cc] = in[(size_t)(r0 + rr + i * 4) * Cc + c0 + cc];
  __syncthreads();
#pragma unroll
  for (int i = 0; i < 16; ++i)
    out[(size_t)(c0 + rr + i * 4) * R + r0 + cc] = (bf16)tile[cc][rr + i * 4];
}

// ------------- GEMM: C[M][N] = A[M][K] * Bt[N][K]^T (m97 structure) -------------
template <typename OutT>
__global__ __launch_bounds__(256) void gemm_bt(const bf16* __restrict__ A,
                                               const bf16* __restrict__ Bt,
                                               OutT* __restrict__ C,
                                               int M, int N, int K) {
  __shared__ bf16 As[128 * 32];
  __shared__ bf16 Bs[128 * 32];
  const int tid = threadIdx.x;
  const int w = tid >> 6, l = tid & 63, quad = l >> 4, l16 = l & 15;
  const int wm = (w >> 1) * 64, wn = (w & 1) * 64;
  const int m0 = blockIdx.y * 128, n0 = blockIdx.x * 128;

  const floatx4 fzero = {0.f, 0.f, 0.f, 0.f};
  floatx4 acc[4][4];
#pragma unroll
  for (int i = 0; i < 4; ++i)
#pragma unroll
    for (int j = 0; j < 4; ++j) acc[i][j] = fzero;

  for (int k0 = 0; k0 < K; k0 += 32) {
#pragma unroll
    for (int i = 0; i < 2; ++i) {
      const int f = (w * 2 + i) * 64 + l;
      const int r = f >> 2, c = f & 3;
      load_lds16(A + (size_t)(m0 + r) * K + k0 + c * 8, As + (w * 2 + i) * 512);
      load_lds16(Bt + (size_t)(n0 + r) * K + k0 + c * 8, Bs + (w * 2 + i) * 512);
    }
    __syncthreads();
    bf16x8 af[4], bfrag[4];
#pragma unroll
    for (int mi = 0; mi < 4; ++mi)
      af[mi] = *(const bf16x8*)(As + (wm + mi * 16 + l16) * 32 + quad * 8);
#pragma unroll
    for (int ni = 0; ni < 4; ++ni)
      bfrag[ni] = *(const bf16x8*)(Bs + (wn + ni * 16 + l16) * 32 + quad * 8);
#pragma unroll
    for (int mi = 0; mi < 4; ++mi)
#pragma unroll
      for (int ni = 0; ni < 4; ++ni)
        acc[mi][ni] = __builtin_amdgcn_mfma_f32_16x16x32_bf16(af[mi], bfrag[ni],
                                                              acc[mi][ni], 0, 0, 0);
    __syncthreads();
  }
#pragma unroll
  for (int mi = 0; mi < 4; ++mi)
#pragma unroll
    for (int ni = 0; ni < 4; ++ni) {
      const int row = m0 + wm + mi * 16 + quad * 4;
      const int col = n0 + wn + ni * 16 + l16;
#pragma unroll
      for (int r = 0; r < 4; ++r)
        C[(size_t)(row + r) * N + col] = (OutT)acc[mi][ni][r];
    }
}

// ------------- RoPE in place on Q and K sections of qkv -------------
__global__ __launch_bounds__(256) void rope_kernel(bf16* __restrict__ qkv) {
  __shared__ float cs_[64], sn_[64];
  const int row = blockIdx.x;       // b*T + t
  const int t = row & (NT - 1);
  if (threadIdx.x < 64) {
    const float invf = exp2f((float)threadIdx.x * (-13.287712379549449f / 64.f));
    float s, c;
    __sincosf((float)t * invf, &s, &c);
    cs_[threadIdx.x] = c; sn_[threadIdx.x] = s;
  }
  __syncthreads();
#pragma unroll
  for (int i = 0; i < 4; ++i) {
    const int idx = threadIdx.x + i * 256;  // 0..1023 -> (h, d<64)
    const int h = idx >> 6, d = idx & 63;
    const float c = cs_[d], s = sn_[d];
    const size_t base = (size_t)row * N3 + h * ND + d;
    {  // Q
      const float x1 = (float)qkv[base], x2 = (float)qkv[base + 64];
      qkv[base]      = (bf16)(x1 * c - x2 * s);
      qkv[base + 64] = (bf16)(x2 * c + x1 * s);
    }
    {  // K
      const float x1 = (float)qkv[base + NC], x2 = (float)qkv[base + NC + 64];
      qkv[base + NC]      = (bf16)(x1 * c - x2 * s);
      qkv[base + NC + 64] = (bf16)(x2 * c + x1 * s);
    }
  }
}

// ------------- V transpose: qkv V-section -> vt[(b,h,d,t)] -------------
__global__ __launch_bounds__(256) void vtrans_kernel(const bf16* __restrict__ qkv,
                                                     bf16* __restrict__ vt) {
  __shared__ bf16 tile[64][136];
  const int t0 = blockIdx.x * 64, h = blockIdx.y, b = blockIdx.z;
  const int tid = threadIdx.x;
#pragma unroll
  for (int i = 0; i < 4; ++i) {
    const int f = tid + i * 256;
    const int r = f >> 4, c8 = f & 15;
    const bf16x8 v = *(const bf16x8*)(qkv + (size_t)(b * NT + t0 + r) * N3 + 2 * NC + h * ND + c8 * 8);
    *(bf16x8*)(&tile[r][c8 * 8]) = v;
  }
  __syncthreads();
#pragma unroll
  for (int i = 0; i < 8; ++i) {
    const int f = tid + i * 256;
    const int d = f >> 4, c4 = f & 15;
    bf16x4 o;
#pragma unroll
    for (int j = 0; j < 4; ++j) o[j] = tile[c4 * 4 + j][d];
    *(bf16x4*)(vt + ((size_t)((b * NH + h) * ND + d)) * NT + t0 + c4 * 4) = o;
  }
}

// ------------- flash attention v2: 32x32 MFMA, S^T/O^T orientation,
//               double-buffered K/V LDS, paired q-tiles for load balance ------
__global__ __launch_bounds__(256) void attn_kernel(const bf16* __restrict__ qkv,
                                                   const bf16* __restrict__ vt,
                                                   bf16* __restrict__ y) {
  __shared__ bf16 Ks[2][64 * 128];   // [buf][kv][d]  16KB each, xor-swizzled 16B chunks
  __shared__ bf16 Vs[2][128 * 64];   // [buf][d][kv]  16KB each, xor-swizzled 16B chunks

  const int pair = blockIdx.x, h = blockIdx.y, b = blockIdx.z;
  const int tid = threadIdx.x;
  const int w = tid >> 6, l = tid & 63, half = l >> 5, l32 = l & 31;
  const float SCL = 0.08838834764831845f * 1.4426950408889634f;  // 1/sqrt(128)*log2(e)

#pragma unroll 1
  for (int pi = 0; pi < 2; ++pi) {
    const int qt = pi ? (15 - pair) : pair;
    const int q0 = qt * 128;
    const int ntiles = qt * 2 + 2;
    const int qg = q0 + w * 32 + l32;   // this lane's q row

    // Q B-fragments from global (RoPE'd): Q[q=l32][d = ks*16 + half*8 + j]
    bf16x8 aq[8];
#pragma unroll
    for (int ks = 0; ks < 8; ++ks)
      aq[ks] = *(const bf16x8*)(qkv + (size_t)(b * NT + qg) * N3 + h * ND + ks * 16 + half * 8);

    floatx16 acc[4];
#pragma unroll
    for (int ni = 0; ni < 4; ++ni)
#pragma unroll
      for (int r = 0; r < 16; ++r) acc[ni][r] = 0.f;
    float mold = -3.0e38f, lsum = 0.f;

    // ---- stage tile 0 into buffer 0 ----
    {
      const int kv0 = 0;
#pragma unroll
      for (int i = 0; i < 4; ++i) {
        const int fb = i * 256 + w * 64, f = fb + l;
        { const int r = f >> 4, cs = f & 15, c = cs ^ (r & 15);
          load_lds16(qkv + (size_t)(b * NT + kv0 + r) * N3 + NC + h * ND + c * 8, &Ks[0][fb * 8]); }
        { const int r = f >> 3, cs = f & 7, c = cs ^ (r & 7);
          load_lds16(vt + ((size_t)((b * NH + h) * ND + r)) * NT + kv0 + c * 8, &Vs[0][fb * 8]); }
      }
    }

#pragma unroll 1
    for (int it = 0; it < ntiles; ++it) {
      const int kv0 = it * 64;
      const int buf = it & 1;
      __syncthreads();   // drains loads for tile it; all waves done reading buf^1

      if (it + 1 < ntiles) {  // prefetch tile it+1 into the other buffer
        const int kvn = kv0 + 64, nb = buf ^ 1;
#pragma unroll
        for (int i = 0; i < 4; ++i) {
          const int fb = i * 256 + w * 64, f = fb + l;
          { const int r = f >> 4, cs = f & 15, c = cs ^ (r & 15);
            load_lds16(qkv + (size_t)(b * NT + kvn + r) * N3 + NC + h * ND + c * 8, &Ks[nb][fb * 8]); }
          { const int r = f >> 3, cs = f & 7, c = cs ^ (r & 7);
            load_lds16(vt + ((size_t)((b * NH + h) * ND + r)) * NT + kvn + c * 8, &Vs[nb][fb * 8]); }
        }
      }

      if (kv0 <= q0 + w * 32 + 31) {  // wave has at least one unmasked kv
        // ---- S^T = K Q^T  (C: kv = (r&3)+8*(r>>2)+4*half, q = l32) ----
        floatx16 st[2];
#pragma unroll
        for (int ki = 0; ki < 2; ++ki)
#pragma unroll
          for (int r = 0; r < 16; ++r) st[ki][r] = 0.f;
#pragma unroll
        for (int ks = 0; ks < 8; ++ks) {
          const int slot = (ks * 2 + half) ^ (l32 & 15);
#pragma unroll
          for (int ki = 0; ki < 2; ++ki) {
            const bf16x8 ak = *(const bf16x8*)(&Ks[buf][(ki * 32 + l32) * 128 + slot * 8]);
            st[ki] = __builtin_amdgcn_mfma_f32_32x32x16_bf16(ak, aq[ks], st[ki], 0, 0, 0);
          }
        }

        // ---- mask + scale + row max (in-lane 32 + one shfl) ----
        float mx = -3.0e38f;
        if (kv0 + 63 > q0 + w * 32) {
#pragma unroll
          for (int ki = 0; ki < 2; ++ki)
#pragma unroll
            for (int r = 0; r < 16; ++r) {
              const int kg = kv0 + ki * 32 + (r & 3) + 8 * (r >> 2) + 4 * half;
              float s = st[ki][r] * SCL;
              s = (kg > qg) ? -3.0e38f : s;
              st[ki][r] = s;
              mx = fmaxf(mx, s);
            }
        } else {
#pragma unroll
          for (int ki = 0; ki < 2; ++ki)
#pragma unroll
            for (int r = 0; r < 16; ++r) {
              const float s = st[ki][r] * SCL;
              st[ki][r] = s;
              mx = fmaxf(mx, s);
            }
        }
        mx = fmaxf(mx, __shfl_xor(mx, 32));

        // ---- online softmax (log2 domain) ----
        const float mnew = fmaxf(mold, mx);
        const float al = exp2f(mold - mnew);
        float rs = 0.f;
#pragma unroll
        for (int ki = 0; ki < 2; ++ki)
#pragma unroll
          for (int r = 0; r < 16; ++r) {
            const float p = exp2f(st[ki][r] - mnew);
            st[ki][r] = p;
            rs += p;
          }
        rs += __shfl_xor(rs, 32);
        lsum = lsum * al + rs;
        mold = mnew;
#pragma unroll
        for (int ni = 0; ni < 4; ++ni)
#pragma unroll
          for (int r = 0; r < 16; ++r) acc[ni][r] *= al;

        // ---- repack P (C-layout) -> B-operand, in-register (16 shfl_xor32) ----
        unsigned pk[2][8];
#pragma unroll
        for (int ki = 0; ki < 2; ++ki)
#pragma unroll
          for (int d = 0; d < 8; ++d)
            pk[ki][d] = pack2(st[ki][2 * d], st[ki][2 * d + 1]);
        bf16x8 bp[4];
#pragma unroll
        for (int s = 0; s < 4; ++s) {
          const int ki = s >> 1, o = (s & 1) * 4;
          const unsigned a0 = pk[ki][o], a1 = pk[ki][o + 1], a2 = pk[ki][o + 2], a3 = pk[ki][o + 3];
          const unsigned s0 = (unsigned)__shfl_xor((int)a0, 32);
          const unsigned s1 = (unsigned)__shfl_xor((int)a1, 32);
          const unsigned s2 = (unsigned)__shfl_xor((int)a2, 32);
          const unsigned s3 = (unsigned)__shfl_xor((int)a3, 32);
          uint4 dw;
          dw.x = half ? s2 : a0;
          dw.y = half ? s3 : a1;
          dw.z = half ? a2 : s0;
          dw.w = half ? a3 : s1;
          bp[s] = __builtin_bit_cast(bf16x8, dw);
        }

        // ---- O^T += V^T P^T  (A = V^T rows, B = P) ----
#pragma unroll
        for (int ni = 0; ni < 4; ++ni) {
          const int rv = ni * 32 + l32;
#pragma unroll
          for (int s = 0; s < 4; ++s) {
            const int slot = (s * 2 + half) ^ (l32 & 7);
            const bf16x8 av = *(const bf16x8*)(&Vs[buf][rv * 64 + slot * 8]);
            acc[ni] = __builtin_amdgcn_mfma_f32_32x32x16_bf16(av, bp[s], acc[ni], 0, 0, 0);
          }
        }
      }
    }

    // ---- epilogue: O^T lane holds (d = ni*32+8*rg+4*half+j, q = l32) ----
    const float inv = 1.f / lsum;
    const size_t orow = (size_t)(b * NT + qg) * NC + h * ND;
#pragma unroll
    for (int ni = 0; ni < 4; ++ni)
#pragma unroll
      for (int rg = 0; rg < 4; ++rg) {
        bf16x4 o;
#pragma unroll
        for (int j = 0; j < 4; ++j) o[j] = (bf16)(acc[ni][rg * 4 + j] * inv);
        *(bf16x4*)(y + orow + ni * 32 + rg * 8 + half * 4) = o;
      }
    __syncthreads();  // protect K/V buffers before next sub-tile overwrites
  }
}

extern "C" void kernel_launch(void* const* d_in, const int* in_sizes, int n_in,
                              void* d_out, int out_size, void* d_ws, size_t ws_size,
                              hipStream_t stream) {
  const float* x      = (const float*)d_in[0];  // (4,2048,2048)
  const float* w_attn = (const float*)d_in[1];  // (2048,6144)
  const float* w_proj = (const float*)d_in[2];  // (2048,2048)
  float* out = (float*)d_out;
  char* ws = (char*)d_ws;

  // workspace layout (aliased): total 176,160,768 B
  bf16* qkv = (bf16*)(ws);                 // [8192][6144]  100,663,296 B
  bf16* xb  = (bf16*)(ws + 100663296);     // [8192][2048]   33,554,432 B
  bf16* vt  = xb;                          // aliases xb (xb dead after GEMM1)
  bf16* wab = (bf16*)(ws + 134217728);     // [6144][2048]   25,165,824 B
  bf16* y   = wab;                         // aliases wab (wab dead after GEMM1)
  bf16* wpb = (bf16*)(ws + 167772160);     // [2048][2048]    8,388,608 B

  cast_f32_bf16<<<dim3(16384), dim3(256), 0, stream>>>(x, xb);
  transpose_cast<<<dim3(96, 32), dim3(256), 0, stream>>>(w_attn, wab, 2048, 6144);
  transpose_cast<<<dim3(32, 32), dim3(256), 0, stream>>>(w_proj, wpb, 2048, 2048);
  gemm_bt<bf16><<<dim3(48, 64), dim3(256), 0, stream>>>(xb, wab, qkv, 8192, 6144, 2048);
  rope_kernel<<<dim3(8192), dim3(256), 0, stream>>>(qkv);
  vtrans_kernel<<<dim3(32, 16, 4), dim3(256), 0, stream>>>(qkv, vt);
  attn_kernel<<<dim3(8, 16, 4), dim3(256), 0, stream>>>(qkv, vt, y);
  gemm_bt<float><<<dim3(16, 64), dim3(256), 0, stream>>>(y, wpb, out, 8192, 2048, 2048);
}

// Round 3
// 674.361 us; speedup vs baseline: 1.4744x; 1.1017x over previous
//
#include <hip/hip_runtime.h>

typedef __bf16 bf16;
typedef __bf16 bf16x8 __attribute__((ext_vector_type(8)));
typedef __bf16 bf16x4 __attribute__((ext_vector_type(4)));
typedef __bf16 bf16x2 __attribute__((ext_vector_type(2)));
typedef float floatx4 __attribute__((ext_vector_type(4)));
typedef float floatx16 __attribute__((ext_vector_type(16)));

#define NB 4
#define NT 2048
#define NC 2048
#define NH 16
#define ND 128
#define QKS 4096   // qk row stride (Q cols 0..2047, K cols 2048..4095)

__device__ __forceinline__ void load_lds16(const void* gptr, void* ldsptr) {
  __builtin_amdgcn_global_load_lds(
      (const __attribute__((address_space(1))) unsigned int*)gptr,
      (__attribute__((address_space(3))) unsigned int*)ldsptr, 16, 0, 0);
}

__device__ __forceinline__ unsigned pack2(float a, float b) {
  bf16x2 v;
  v[0] = (bf16)a; v[1] = (bf16)b;
  return __builtin_bit_cast(unsigned, v);
}

// ---------------- cast fp32 -> bf16 (4 elts/thread) ----------------
__global__ __launch_bounds__(256) void cast_f32_bf16(const float* __restrict__ in,
                                                     bf16* __restrict__ out) {
  const int i = blockIdx.x * 256 + threadIdx.x;
  const float4 v = ((const float4*)in)[i];
  bf16x4 o;
  o[0] = (bf16)v.x; o[1] = (bf16)v.y; o[2] = (bf16)v.z; o[3] = (bf16)v.w;
  ((bf16x4*)out)[i] = o;
}

// ------ transpose+cast: in[R][Cc] f32 -> out[Cc][R] bf16, 128r x 64c tiles ------
__global__ __launch_bounds__(256) void transpose_cast(const float* __restrict__ in,
                                                      bf16* __restrict__ out,
                                                      int R, int Cc) {
  __shared__ float tile[128][65];
  const int r0 = blockIdx.y * 128, c0 = blockIdx.x * 64;
  const int rr = threadIdx.x >> 6, cc = threadIdx.x & 63;
#pragma unroll
  for (int i = 0; i < 32; ++i)
    tile[rr + i * 4][cc] = in[(size_t)(r0 + rr + i * 4) * Cc + c0 + cc];
  __syncthreads();
  const int rv = threadIdx.x & 63, halfr = (threadIdx.x >> 6) & 1, crh = threadIdx.x >> 7;
#pragma unroll
  for (int i = 0; i < 32; ++i) {
    const int cr = crh * 32 + i;
    out[(size_t)(c0 + cr) * R + r0 + halfr * 64 + rv] = (bf16)tile[halfr * 64 + rv][cr];
  }
}

// ------------- GEMM: C[M][N] = A[M][K]*Bt[N][K]^T, BK=64, swizzled LDS.
//   EPI==0: plain store to C (OutT).
//   EPI==1: fused epilogue -> Q/K tiles RoPE'd into qk, V tiles transposed into vt.
template <int EPI, typename OutT>
__global__ __launch_bounds__(256) void gemm_bt(const bf16* __restrict__ A,
                                               const bf16* __restrict__ Bt,
                                               OutT* __restrict__ C,
                                               bf16* __restrict__ qk,
                                               bf16* __restrict__ vt,
                                               int M, int N, int K, int NTX) {
  __shared__ bf16 smem[128 * 132];   // loop: As=smem[0..8191], Bs=smem[8192..16383]; epi: 128x130 tile
  __shared__ float invf_s[64];
  bf16* As = smem;
  bf16* Bs = smem + 128 * 64;
  const int tid = threadIdx.x;
  const int w = tid >> 6, l = tid & 63, quad = l >> 4, l16 = l & 15;
  const int wm = (w >> 1) * 64, wn = (w & 1) * 64;

  // band swizzle: 8 consecutive M-tiles share B-panels in L2
  const int per = 8 * NTX;
  const int band = blockIdx.x / per, rem = blockIdx.x - band * per;
  const int by = band * 8 + (rem & 7), bx = rem >> 3;
  const int m0 = by * 128, n0 = bx * 128;

  if (EPI == 1 && tid < 64)
    invf_s[tid] = exp2f(-(float)tid * 0.20762050593046014f);  // 10000^(-d/64)

  const floatx4 fzero = {0.f, 0.f, 0.f, 0.f};
  floatx4 acc[4][4];
#pragma unroll
  for (int i = 0; i < 4; ++i)
#pragma unroll
    for (int j = 0; j < 4; ++j) acc[i][j] = fzero;

  for (int k0 = 0; k0 < K; k0 += 64) {
#pragma unroll
    for (int i = 0; i < 4; ++i) {
      const int fb = (w * 4 + i) * 64;
      const int f = fb + l;
      const int r = f >> 3, cs = f & 7, c = cs ^ (r & 7);  // swizzled chunk
      load_lds16(A + (size_t)(m0 + r) * K + k0 + c * 8, As + fb * 8);
      load_lds16(Bt + (size_t)(n0 + r) * K + k0 + c * 8, Bs + fb * 8);
    }
    __syncthreads();
#pragma unroll
    for (int kk = 0; kk < 2; ++kk) {
      bf16x8 af[4], bfr[4];
#pragma unroll
      for (int mi = 0; mi < 4; ++mi) {
        const int row = wm + mi * 16 + l16;
        af[mi] = *(const bf16x8*)(As + row * 64 + ((kk * 4 + quad) ^ (row & 7)) * 8);
      }
#pragma unroll
      for (int ni = 0; ni < 4; ++ni) {
        const int row = wn + ni * 16 + l16;
        bfr[ni] = *(const bf16x8*)(Bs + row * 64 + ((kk * 4 + quad) ^ (row & 7)) * 8);
      }
#pragma unroll
      for (int mi = 0; mi < 4; ++mi)
#pragma unroll
        for (int ni = 0; ni < 4; ++ni)
          acc[mi][ni] = __builtin_amdgcn_mfma_f32_16x16x32_bf16(af[mi], bfr[ni],
                                                                acc[mi][ni], 0, 0, 0);
    }
    __syncthreads();
  }

  if constexpr (EPI == 0) {
    // C/D layout: col = lane&15, row = quad*4 + reg
#pragma unroll
    for (int mi = 0; mi < 4; ++mi)
#pragma unroll
      for (int ni = 0; ni < 4; ++ni) {
        const int row = m0 + wm + mi * 16 + quad * 4;
        const int col = n0 + wn + ni * 16 + l16;
#pragma unroll
        for (int r = 0; r < 4; ++r)
          C[(size_t)(row + r) * N + col] = (OutT)acc[mi][ni][r];
      }
  } else {
    // stage the 128x128 output tile in LDS (stride 130)
    bf16* Tl = smem;
#pragma unroll
    for (int mi = 0; mi < 4; ++mi)
#pragma unroll
      for (int ni = 0; ni < 4; ++ni) {
        const int rloc = wm + mi * 16 + quad * 4;
        const int cloc = wn + ni * 16 + l16;
#pragma unroll
        for (int r = 0; r < 4; ++r)
          Tl[(rloc + r) * 130 + cloc] = (bf16)acc[mi][ni][r];
      }
    __syncthreads();

    const int nt = n0 >> 7;
    if (nt < 32) {
      // ---- Q or K tile: apply RoPE, store to qk[(m0+r)][n0 + c] ----
      const int r = tid >> 1, hd = tid & 1;
      const int t = (m0 & (NT - 1)) + r;
      const float tt = (float)t;
      bf16* dst = qk + (size_t)(m0 + r) * QKS + n0;
#pragma unroll
      for (int j8 = 0; j8 < 2; ++j8) {
        const int d0 = hd * 32 + j8 * 16;
        bf16x8 lo[2], hi[2];
#pragma unroll
        for (int half8 = 0; half8 < 2; ++half8) {
#pragma unroll
          for (int jj = 0; jj < 8; ++jj) {
            const int d = d0 + half8 * 8 + jj;
            const float x1 = (float)Tl[r * 130 + d];
            const float x2 = (float)Tl[r * 130 + d + 64];
            float s, c;
            __sincosf(tt * invf_s[d], &s, &c);
            lo[half8][jj] = (bf16)(x1 * c - x2 * s);
            hi[half8][jj] = (bf16)(x2 * c + x1 * s);
          }
          *(bf16x8*)(dst + d0 + half8 * 8) = lo[half8];
          *(bf16x8*)(dst + d0 + half8 * 8 + 64) = hi[half8];
        }
      }
    } else {
      // ---- V tile: transpose into vt[(b*16+h)*128 + d][t] ----
      const int h = nt - 32;
      const int b = m0 >> 11;           // m-tile never straddles batch (2048/128=16)
      const int t0 = m0 & (NT - 1);
      const int vbase = (b * NH + h) * ND;
#pragma unroll
      for (int ii = 0; ii < 8; ++ii) {
        const int dd = (tid >> 4) + ii * 16;
        const int ch = tid & 15;
        bf16x8 o;
#pragma unroll
        for (int j = 0; j < 8; ++j) o[j] = Tl[(ch * 8 + j) * 130 + dd];
        *(bf16x8*)(vt + (size_t)(vbase + dd) * NT + t0 + ch * 8) = o;
      }
    }
  }
}

// ------------- flash attention: 32x32 MFMA, S^T/O^T orientation,
//               double-buffered K/V LDS, paired q-tiles for load balance ------
__global__ __launch_bounds__(256) void attn_kernel(const bf16* __restrict__ qk,
                                                   const bf16* __restrict__ vt,
                                                   bf16* __restrict__ y) {
  __shared__ bf16 Ks[2][64 * 128];   // [buf][kv][d]  xor-swizzled 16B chunks
  __shared__ bf16 Vs[2][128 * 64];   // [buf][d][kv]  xor-swizzled 16B chunks

  const int pair = blockIdx.x, h = blockIdx.y, b = blockIdx.z;
  const int tid = threadIdx.x;
  const int w = tid >> 6, l = tid & 63, half = l >> 5, l32 = l & 31;
  const float SCL = 0.08838834764831845f * 1.4426950408889634f;  // 1/sqrt(128)*log2(e)

#pragma unroll 1
  for (int pi = 0; pi < 2; ++pi) {
    const int qt = pi ? (15 - pair) : pair;
    const int q0 = qt * 128;
    const int ntiles = qt * 2 + 2;
    const int qg = q0 + w * 32 + l32;   // this lane's q row

    // Q B-fragments from global (RoPE'd): Q[q=l32][d = ks*16 + half*8 + j]
    bf16x8 aq[8];
#pragma unroll
    for (int ks = 0; ks < 8; ++ks)
      aq[ks] = *(const bf16x8*)(qk + (size_t)(b * NT + qg) * QKS + h * ND + ks * 16 + half * 8);

    floatx16 acc[4];
#pragma unroll
    for (int ni = 0; ni < 4; ++ni)
#pragma unroll
      for (int r = 0; r < 16; ++r) acc[ni][r] = 0.f;
    float mold = -3.0e38f, lsum = 0.f;

    // ---- stage tile 0 into buffer 0 ----
    {
#pragma unroll
      for (int i = 0; i < 4; ++i) {
        const int fb = i * 256 + w * 64, f = fb + l;
        { const int r = f >> 4, cs = f & 15, c = cs ^ (r & 15);
          load_lds16(qk + (size_t)(b * NT + r) * QKS + NC + h * ND + c * 8, &Ks[0][fb * 8]); }
        { const int r = f >> 3, cs = f & 7, c = cs ^ (r & 7);
          load_lds16(vt + ((size_t)((b * NH + h) * ND + r)) * NT + c * 8, &Vs[0][fb * 8]); }
      }
    }

#pragma unroll 1
    for (int it = 0; it < ntiles; ++it) {
      const int kv0 = it * 64;
      const int buf = it & 1;
      __syncthreads();   // drains loads for tile it; all waves done reading buf^1

      if (it + 1 < ntiles) {  // prefetch tile it+1 into the other buffer
        const int kvn = kv0 + 64, nb = buf ^ 1;
#pragma unroll
        for (int i = 0; i < 4; ++i) {
          const int fb = i * 256 + w * 64, f = fb + l;
          { const int r = f >> 4, cs = f & 15, c = cs ^ (r & 15);
            load_lds16(qk + (size_t)(b * NT + kvn + r) * QKS + NC + h * ND + c * 8, &Ks[nb][fb * 8]); }
          { const int r = f >> 3, cs = f & 7, c = cs ^ (r & 7);
            load_lds16(vt + ((size_t)((b * NH + h) * ND + r)) * NT + kvn + c * 8, &Vs[nb][fb * 8]); }
        }
      }

      if (kv0 <= q0 + w * 32 + 31) {  // wave has at least one unmasked kv
        // ---- S^T = K Q^T  (C: kv = (r&3)+8*(r>>2)+4*half, q = l32) ----
        floatx16 st[2];
#pragma unroll
        for (int ki = 0; ki < 2; ++ki)
#pragma unroll
          for (int r = 0; r < 16; ++r) st[ki][r] = 0.f;
#pragma unroll
        for (int ks = 0; ks < 8; ++ks) {
          const int slot = (ks * 2 + half) ^ (l32 & 15);
#pragma unroll
          for (int ki = 0; ki < 2; ++ki) {
            const bf16x8 ak = *(const bf16x8*)(&Ks[buf][(ki * 32 + l32) * 128 + slot * 8]);
            st[ki] = __builtin_amdgcn_mfma_f32_32x32x16_bf16(ak, aq[ks], st[ki], 0, 0, 0);
          }
        }

        // ---- mask + scale + row max (in-lane 32 + one shfl) ----
        float mx = -3.0e38f;
        if (kv0 + 63 > q0 + w * 32) {
#pragma unroll
          for (int ki = 0; ki < 2; ++ki)
#pragma unroll
            for (int r = 0; r < 16; ++r) {
              const int kg = kv0 + ki * 32 + (r & 3) + 8 * (r >> 2) + 4 * half;
              float s = st[ki][r] * SCL;
              s = (kg > qg) ? -3.0e38f : s;
              st[ki][r] = s;
              mx = fmaxf(mx, s);
            }
        } else {
#pragma unroll
          for (int ki = 0; ki < 2; ++ki)
#pragma unroll
            for (int r = 0; r < 16; ++r) {
              const float s = st[ki][r] * SCL;
              st[ki][r] = s;
              mx = fmaxf(mx, s);
            }
        }
        mx = fmaxf(mx, __shfl_xor(mx, 32));

        // ---- online softmax (log2 domain) ----
        const float mnew = fmaxf(mold, mx);
        const float al = exp2f(mold - mnew);
        float rs = 0.f;
#pragma unroll
        for (int ki = 0; ki < 2; ++ki)
#pragma unroll
          for (int r = 0; r < 16; ++r) {
            const float p = exp2f(st[ki][r] - mnew);
            st[ki][r] = p;
            rs += p;
          }
        rs += __shfl_xor(rs, 32);
        lsum = lsum * al + rs;
        mold = mnew;
#pragma unroll
        for (int ni = 0; ni < 4; ++ni)
#pragma unroll
          for (int r = 0; r < 16; ++r) acc[ni][r] *= al;

        // ---- repack P (C-layout) -> B-operand, in-register (16 shfl_xor32) ----
        unsigned pk[2][8];
#pragma unroll
        for (int ki = 0; ki < 2; ++ki)
#pragma unroll
          for (int d = 0; d < 8; ++d)
            pk[ki][d] = pack2(st[ki][2 * d], st[ki][2 * d + 1]);
        bf16x8 bp[4];
#pragma unroll
        for (int s = 0; s < 4; ++s) {
          const int ki = s >> 1, o = (s & 1) * 4;
          const unsigned a0 = pk[ki][o], a1 = pk[ki][o + 1], a2 = pk[ki][o + 2], a3 = pk[ki][o + 3];
          const unsigned s0 = (unsigned)__shfl_xor((int)a0, 32);
          const unsigned s1 = (unsigned)__shfl_xor((int)a1, 32);
          const unsigned s2 = (unsigned)__shfl_xor((int)a2, 32);
          const unsigned s3 = (unsigned)__shfl_xor((int)a3, 32);
          uint4 dw;
          dw.x = half ? s2 : a0;
          dw.y = half ? s3 : a1;
          dw.z = half ? a2 : s0;
          dw.w = half ? a3 : s1;
          bp[s] = __builtin_bit_cast(bf16x8, dw);
        }

        // ---- O^T += V^T P^T  (A = V^T rows, B = P) ----
#pragma unroll
        for (int ni = 0; ni < 4; ++ni) {
          const int rv = ni * 32 + l32;
#pragma unroll
          for (int s = 0; s < 4; ++s) {
            const int slot = (s * 2 + half) ^ (l32 & 7);
            const bf16x8 av = *(const bf16x8*)(&Vs[buf][rv * 64 + slot * 8]);
            acc[ni] = __builtin_amdgcn_mfma_f32_32x32x16_bf16(av, bp[s], acc[ni], 0, 0, 0);
          }
        }
      }
    }

    // ---- epilogue: O^T lane holds (d = ni*32+8*rg+4*half+j, q = l32) ----
    const float inv = 1.f / lsum;
    const size_t orow = (size_t)(b * NT + qg) * NC + h * ND;
#pragma unroll
    for (int ni = 0; ni < 4; ++ni)
#pragma unroll
      for (int rg = 0; rg < 4; ++rg) {
        bf16x4 o;
#pragma unroll
        for (int j = 0; j < 4; ++j) o[j] = (bf16)(acc[ni][rg * 4 + j] * inv);
        *(bf16x4*)(y + orow + ni * 32 + rg * 8 + half * 4) = o;
      }
    __syncthreads();  // protect K/V buffers before next sub-tile overwrites
  }
}

extern "C" void kernel_launch(void* const* d_in, const int* in_sizes, int n_in,
                              void* d_out, int out_size, void* d_ws, size_t ws_size,
                              hipStream_t stream) {
  const float* x      = (const float*)d_in[0];  // (4,2048,2048)
  const float* w_attn = (const float*)d_in[1];  // (2048,6144)
  const float* w_proj = (const float*)d_in[2];  // (2048,2048)
  float* out = (float*)d_out;
  char* ws = (char*)d_ws;

  // workspace layout: total 176,160,768 B (same proven footprint)
  bf16* qk  = (bf16*)(ws);                 // [8192][4096] RoPE'd Q|K   67,108,864 B
  bf16* vt  = (bf16*)(ws + 67108864);      // [4*16*128][2048] V^T      33,554,432 B
  bf16* xb  = (bf16*)(ws + 100663296);     // [8192][2048]              33,554,432 B
  bf16* wab = (bf16*)(ws + 134217728);     // [6144][2048]              25,165,824 B
  bf16* y   = wab;                         // aliases wab (dead after GEMM1), 33,554,432 B ends at 167,772,160
  bf16* wpb = (bf16*)(ws + 167772160);     // [2048][2048]               8,388,608 B

  cast_f32_bf16<<<dim3(16384), dim3(256), 0, stream>>>(x, xb);
  transpose_cast<<<dim3(96, 16), dim3(256), 0, stream>>>(w_attn, wab, 2048, 6144);
  transpose_cast<<<dim3(32, 16), dim3(256), 0, stream>>>(w_proj, wpb, 2048, 2048);
  gemm_bt<1, float><<<dim3(3072), dim3(256), 0, stream>>>(xb, wab, (float*)nullptr, qk, vt,
                                                          8192, 6144, 2048, 48);
  attn_kernel<<<dim3(8, 16, 4), dim3(256), 0, stream>>>(qk, vt, y);
  gemm_bt<0, float><<<dim3(1024), dim3(256), 0, stream>>>(y, wpb, out, nullptr, nullptr,
                                                          8192, 2048, 2048, 16);
}